// Round 11
// baseline (233.964 us; speedup 1.0000x reference)
//
#include <hip/hip_runtime.h>
#include <hip/hip_bf16.h>

// NT-Xent (CLIP) loss, N=16384 D=256 fp32 in, 3 fp32 out.
// loss_vu = mean_i( log(sum_j exp(sim_ij)) - sim_ii ), sim = (v̂·û^T)/T
// Logits bounded by 1/T=14.29 -> no max subtraction needed.
//
// R2..R9: LDS-staged 2-phase variants plateau 224-280us.
// R10: FRAGMENT-MAJOR layout (K1 packs V',U' in MFMA fragment order; K2
//     LDS-free barrier-free). R11: depth-4 B ring: 196us. R12: 64 rows/
//     block (A=128 VGPR resident), depth-2 ring: 155us, MfmaUtil 40%.
// R13: the vmcnt FIFO poison. Per jt the 4 colsum global atomicAdds are
//     issued BETWEEN B-load clusters; vmcnt retires IN ORDER, so next
//     jt's B-consume waitcnt is gated by slow (~600cyc, contended)
//     atomics ahead of it in the FIFO -> ~5k cyc/jt stall. Fix: colsum
//     -> 64KB LDS (plain writes; each col written exactly once per
//     block: unique (jt,w,ni,l15)), flushed once post-loop with
//     coalesced atomics. DS ops use lgkmcnt -> vmcnt FIFO = pure loads.
//     Also: two-stage finalize (64-block partials + 1-thread final).
//     Gates: LDS=65536, VGPR ~128 (no spill), MfmaUtil >= 50%.

#define D_DIM 256

constexpr float INV_T = 1.0f / 0.07f;
constexpr float EXP2_SCALE = 1.44269504088896340736f / 0.07f;  // log2(e)/T

typedef __bf16 bf16x8 __attribute__((ext_vector_type(8)));
typedef float f32x4 __attribute__((ext_vector_type(4)));

// ---------------------------------------------------------------------------
// Kernel 1: L2-normalize fp32 -> bf16 in FRAGMENT-MAJOR layout.
// One wave = 2 rows: lane = sub(1)|pos(5); lane handles 8 elems
// [pos*8, +8) of row (blk*8 + wave*2 + sub). Norm-reduce over the
// 32-lane half. Fragment write: row r -> group g=r>>4, slot l15=r&15;
// chunk pos -> ks=pos>>2, quad=pos&3; offset (g*8+ks)*512+(quad*16+l15)*8.
// V' pre-scaled by EXP2_SCALE; diag from unscaled v,u; zeroes row/colsum
// and the 3 finalize partials. (R10..R12-verified: absmax 0.)
// ---------------------------------------------------------------------------
__global__ __launch_bounds__(256) void normalize_kernel(
    const float* __restrict__ img, const float* __restrict__ txt,
    __hip_bfloat16* __restrict__ Vf, __hip_bfloat16* __restrict__ Uf,
    float* __restrict__ diagarr, float* __restrict__ rowsum,
    float* __restrict__ colsum, float* __restrict__ partials) {
  const int wave = threadIdx.x >> 6;
  const int lane = threadIdx.x & 63;
  const int sub = lane >> 5;   // 0/1: which of the wave's two rows
  const int pos = lane & 31;   // 8-elem chunk index within the row
  const int row = blockIdx.x * 8 + wave * 2 + sub;
  const size_t base = (size_t)row * D_DIM + pos * 8;

  const float4 i0 = *reinterpret_cast<const float4*>(&img[base]);
  const float4 i1 = *reinterpret_cast<const float4*>(&img[base + 4]);
  const float4 t0 = *reinterpret_cast<const float4*>(&txt[base]);
  const float4 t1 = *reinterpret_cast<const float4*>(&txt[base + 4]);

  float a = i0.x * i0.x + i0.y * i0.y + i0.z * i0.z + i0.w * i0.w +
            i1.x * i1.x + i1.y * i1.y + i1.z * i1.z + i1.w * i1.w;
  float b = t0.x * t0.x + t0.y * t0.y + t0.z * t0.z + t0.w * t0.w +
            t1.x * t1.x + t1.y * t1.y + t1.z * t1.z + t1.w * t1.w;
#pragma unroll
  for (int off = 1; off < 32; off <<= 1) {
    a += __shfl_xor(a, off, 64);
    b += __shfl_xor(b, off, 64);
  }
  const float si = 1.0f / fmaxf(sqrtf(a), 1e-8f);
  const float st = 1.0f / fmaxf(sqrtf(b), 1e-8f);

  const float vs = si * EXP2_SCALE;  // V pre-scaled by log2e/T
  __hip_bfloat16 vb8[8] = {
      __float2bfloat16(i0.x * vs), __float2bfloat16(i0.y * vs),
      __float2bfloat16(i0.z * vs), __float2bfloat16(i0.w * vs),
      __float2bfloat16(i1.x * vs), __float2bfloat16(i1.y * vs),
      __float2bfloat16(i1.z * vs), __float2bfloat16(i1.w * vs)};
  __hip_bfloat16 ub8[8] = {
      __float2bfloat16(t0.x * st), __float2bfloat16(t0.y * st),
      __float2bfloat16(t0.z * st), __float2bfloat16(t0.w * st),
      __float2bfloat16(t1.x * st), __float2bfloat16(t1.y * st),
      __float2bfloat16(t1.z * st), __float2bfloat16(t1.w * st)};

  const int g = row >> 4, l15r = row & 15;
  const int ks = pos >> 2, quad = pos & 3;
  const size_t foff = (size_t)(g * 8 + ks) * 512 + (quad * 16 + l15r) * 8;
  *reinterpret_cast<uint4*>(&Vf[foff]) = *reinterpret_cast<uint4*>(vb8);
  *reinterpret_cast<uint4*>(&Uf[foff]) = *reinterpret_cast<uint4*>(ub8);

  // diag v̂_i·û_i (unscaled)
  float d = (i0.x * si) * (t0.x * st) + (i0.y * si) * (t0.y * st) +
            (i0.z * si) * (t0.z * st) + (i0.w * si) * (t0.w * st) +
            (i1.x * si) * (t1.x * st) + (i1.y * si) * (t1.y * st) +
            (i1.z * si) * (t1.z * st) + (i1.w * si) * (t1.w * st);
#pragma unroll
  for (int off = 1; off < 32; off <<= 1) d += __shfl_xor(d, off, 64);
  if (pos == 0) diagarr[row] = d;

  if (threadIdx.x < 8) {
    rowsum[blockIdx.x * 8 + threadIdx.x] = 0.0f;
    colsum[blockIdx.x * 8 + threadIdx.x] = 0.0f;
  }
  if (blockIdx.x == 0 && threadIdx.x < 4) partials[threadIdx.x] = 0.0f;
}

// ---------------------------------------------------------------------------
// Kernel 2: barrier-free streaming MFMA GEMM + online exp2 sums.
// Block = 64 rows (groups 4b..4b+3) x all N cols; 8 waves; wave w covers
// cols [jt*512 + w*64, +64) of each 512-col j-tile (njt = 32).
// A-frags a[4][8] (128 VGPR) resident. B: depth-2 ring bb[2][4]; at step
// ks issue load(ks+1) into the other bank, sched_barrier(0) pin, consume
// bank ks&1. ks=7 prefetches next jt's ks0 (covered by the epilogue).
// colsum: LDS colbuf[16384] plain writes (one writer per col), coalesced
// atomic flush after the jt loop -> vmcnt FIFO stays pure loads.
// acc layout (verified): row = mi*16 + quad*4 + r, col = ni*16 + l15.
// ---------------------------------------------------------------------------
__global__ __launch_bounds__(512, 2) void gemm_lse_kernel(
    const __hip_bfloat16* __restrict__ Vf, const __hip_bfloat16* __restrict__ Uf,
    float* __restrict__ rowsum, float* __restrict__ colsum, int n) {
  __shared__ float colbuf[16384];  // 64 KB; each entry written exactly once

  const int tid = threadIdx.x;
  const int lane = tid & 63;
  const int w = tid >> 6;        // 0..7
  const int quad = lane >> 4;
  const int l15 = lane & 15;
  const int b = blockIdx.x;
  const int njt = n >> 9;        // j-tiles of 512 cols

  // A fragments for rows [b*64, +64): groups 4b..4b+3, all K, once.
  bf16x8 a[4][8];
#pragma unroll
  for (int mi = 0; mi < 4; ++mi)
#pragma unroll
    for (int ks = 0; ks < 8; ++ks)
      a[mi][ks] = *reinterpret_cast<const bf16x8*>(
          Vf + (size_t)((4 * b + mi) * 8 + ks) * 512 + lane * 8);

  float rs[4][4] = {};  // rowsum partials (mi, r), all jt

  // B base for this wave: col group = jt*32 + w*4 + ni; frag at
  // (group*8 + ks)*512 + lane*8.
  const __hip_bfloat16* Ub = Uf + (size_t)(w * 4) * 8 * 512 + lane * 8;

  // Depth-2 ring. Prologue: jt0 ks0 -> bank 0.
  bf16x8 bb[2][4];
#pragma unroll
  for (int ni = 0; ni < 4; ++ni)
    bb[0][ni] = *reinterpret_cast<const bf16x8*>(Ub + (size_t)(ni * 8) * 512);

  for (int jt = 0; jt < njt; ++jt) {
    const size_t jb = (size_t)jt * (32 * 8 * 512);
    const size_t jbn = (jt < njt - 1) ? jb + 32 * 8 * 512 : 0;  // wrap: jt0
    f32x4 acc[4][4] = {};

#pragma unroll
    for (int ks = 0; ks < 8; ++ks) {
      // issue load for step ks+1 into the other bank (free since ks-1)
      {
        const size_t pjb = (ks < 7) ? jb : jbn;
        const int pks = (ks < 7) ? ks + 1 : 0;
#pragma unroll
        for (int ni = 0; ni < 4; ++ni)
          bb[(ks + 1) & 1][ni] = *reinterpret_cast<const bf16x8*>(
              Ub + pjb + (size_t)(ni * 8 + pks) * 512);
        __builtin_amdgcn_sched_barrier(0);
      }
      // consume bank ks&1 (waitcnt for its step-(ks-1) loads; FIFO has
      // only loads -> wait resolves at L2-hit latency)
#pragma unroll
      for (int mi = 0; mi < 4; ++mi)
#pragma unroll
        for (int ni = 0; ni < 4; ++ni)
          acc[mi][ni] = __builtin_amdgcn_mfma_f32_16x16x32_bf16(
              a[mi][ks], bb[ks & 1][ni], acc[mi][ni], 0, 0, 0);
    }

    // per-jt epilogue: exp2, rowsum regs, colsum -> LDS (no atomics here).
    float cs0 = 0.f, cs1 = 0.f, cs2 = 0.f, cs3 = 0.f;
#pragma unroll
    for (int mi = 0; mi < 4; ++mi)
#pragma unroll
      for (int r = 0; r < 4; ++r) {
        const float e0 = __builtin_amdgcn_exp2f(acc[mi][0][r]);
        const float e1 = __builtin_amdgcn_exp2f(acc[mi][1][r]);
        const float e2 = __builtin_amdgcn_exp2f(acc[mi][2][r]);
        const float e3 = __builtin_amdgcn_exp2f(acc[mi][3][r]);
        rs[mi][r] += e0 + e1 + e2 + e3;
        cs0 += e0; cs1 += e1; cs2 += e2; cs3 += e3;
      }
    float csa[4] = {cs0, cs1, cs2, cs3};
#pragma unroll
    for (int ni = 0; ni < 4; ++ni) {
      float c = csa[ni];
      c += __shfl_xor(c, 16, 64);
      c += __shfl_xor(c, 32, 64);
      if (lane < 16)
        colbuf[jt * 512 + w * 64 + ni * 16 + l15] = c;  // single writer
    }
  }

  // flush colsum once: coalesced atomics, off the jt critical path.
  __syncthreads();
  for (int i = tid; i < n; i += 512) atomicAdd(&colsum[i], colbuf[i]);

  // final rowsum: reduce over the 16 l15 lanes; 8 waves meet via atomics.
#pragma unroll
  for (int mi = 0; mi < 4; ++mi)
#pragma unroll
    for (int r = 0; r < 4; ++r) {
      float v = rs[mi][r];
      v += __shfl_xor(v, 1, 64);
      v += __shfl_xor(v, 2, 64);
      v += __shfl_xor(v, 4, 64);
      v += __shfl_xor(v, 8, 64);
      if (l15 == 0)
        atomicAdd(&rowsum[b * 64 + mi * 16 + quad * 4 + r], v);
    }
}

// ---------------------------------------------------------------------------
// Kernel 3a: parallel partial reduction of log(rowsum), log(colsum), diag.
// ---------------------------------------------------------------------------
__global__ __launch_bounds__(256) void finalize_partial(
    const float* __restrict__ rowsum, const float* __restrict__ colsum,
    const float* __restrict__ diagarr, float* __restrict__ partials, int n) {
  float sr = 0.0f, sc = 0.0f, sd = 0.0f;
  for (int i = blockIdx.x * 256 + threadIdx.x; i < n; i += gridDim.x * 256) {
    sr += __logf(rowsum[i]);
    sc += __logf(colsum[i]);
    sd += diagarr[i];
  }
#pragma unroll
  for (int off = 1; off < 64; off <<= 1) {
    sr += __shfl_xor(sr, off, 64);
    sc += __shfl_xor(sc, off, 64);
    sd += __shfl_xor(sd, off, 64);
  }
  if ((threadIdx.x & 63) == 0) {
    atomicAdd(&partials[0], sr);
    atomicAdd(&partials[1], sc);
    atomicAdd(&partials[2], sd);
  }
}

// ---------------------------------------------------------------------------
// Kernel 3b: final 3-float output from the totals.
// ---------------------------------------------------------------------------
__global__ void finalize_final(const float* __restrict__ partials,
                               float* __restrict__ out, int n) {
  const float invN = 1.0f / (float)n;
  const float dm = partials[2] * INV_T * invN;  // mean diag logit
  const float lvu = partials[0] * invN - dm;
  const float luv = partials[1] * invN - dm;
  out[0] = 0.5f * lvu + 0.5f * luv;  // WEIGHT = 0.5
  out[1] = lvu;
  out[2] = luv;
}

extern "C" void kernel_launch(void* const* d_in, const int* in_sizes, int n_in,
                              void* d_out, int out_size, void* d_ws, size_t ws_size,
                              hipStream_t stream) {
  const float* img = (const float*)d_in[0];
  const float* txt = (const float*)d_in[1];
  float* out = (float*)d_out;
  const int N = in_sizes[0] / D_DIM;  // 16384

  char* ws = (char*)d_ws;
  __hip_bfloat16* Vf = (__hip_bfloat16*)ws;                             // 8MB
  __hip_bfloat16* Uf = (__hip_bfloat16*)(ws + (size_t)N * D_DIM * 2);   // 8MB
  float* rowsum = (float*)(ws + (size_t)N * D_DIM * 4);
  float* colsum = rowsum + N;
  float* diagarr = colsum + N;
  float* partials = diagarr + N;  // 4 floats

  // rowsum/colsum/partials zeroed inside normalize_kernel
  normalize_kernel<<<N / 8, 256, 0, stream>>>(img, txt, Vf, Uf, diagarr,
                                              rowsum, colsum, partials);

  gemm_lse_kernel<<<N / 64, 512, 0, stream>>>(Vf, Uf, rowsum, colsum, N);

  finalize_partial<<<64, 256, 0, stream>>>(rowsum, colsum, diagarr, partials,
                                           N);
  finalize_final<<<1, 1, 0, stream>>>(partials, out, N);
}